// Round 12
// baseline (175.983 us; speedup 1.0000x reference)
//
#include <hip/hip_runtime.h>
#include <hip/hip_bf16.h>
#include <stdint.h>
#include <stddef.h>

typedef __bf16 bf16_t;
typedef __attribute__((ext_vector_type(2))) __bf16 bf16x2;
typedef __attribute__((ext_vector_type(4))) __bf16 bf16x4;
typedef __attribute__((ext_vector_type(8))) __bf16 bf16x8;
typedef __attribute__((ext_vector_type(4))) float floatx4;
typedef __attribute__((ext_vector_type(16))) float floatx16;
typedef __attribute__((ext_vector_type(4))) int intx4;

#define GLD16(gp, lp) __builtin_amdgcn_global_load_lds(                      \
    (__attribute__((address_space(1))) void*)(gp),                           \
    (__attribute__((address_space(3))) void*)(lp), 16, 0, 0)

// ---------------------------------------------------------------------------
// Fused prep: [0,2048) x f32->bf16 | [2048,2816) transpose_w | [2816,3072) transpose_wo
// Q weights (z==0) pre-scaled by (1/sqrt(64))*log2(e).
// ---------------------------------------------------------------------------
__global__ __launch_bounds__(256) void prep(
    const float* __restrict__ x, const float* __restrict__ Wq,
    const float* __restrict__ Wk, const float* __restrict__ Wv,
    const float* __restrict__ Wo, bf16_t* __restrict__ XB,
    bf16_t* __restrict__ WT, bf16_t* __restrict__ WoT) {
  __shared__ bf16_t t[64][65];
  int bx = blockIdx.x;
  const int tid = threadIdx.x;
  if (bx < 2048) {  // convert x
    const int i = (bx * 256 + tid) * 8;
    const float4 v0 = *(const float4*)(x + i);
    const float4 v1 = *(const float4*)(x + i + 4);
    bf16x8 o = {(bf16_t)v0.x, (bf16_t)v0.y, (bf16_t)v0.z, (bf16_t)v0.w,
                (bf16_t)v1.x, (bf16_t)v1.y, (bf16_t)v1.z, (bf16_t)v1.w};
    *(bf16x8*)(XB + i) = o;
    return;
  }
  bx -= 2048;
  const int g = tid >> 6, l = tid & 63;
  if (bx < 768) {  // Wq/Wk/Wv [16][1024][64] -> WT [3072][1024]
    const int d0 = (bx & 15) * 64, h = (bx >> 4) & 15, z = bx >> 8;
    const float* W = (z == 0) ? Wq : (z == 1) ? Wk : Wv;
    const float scl = (z == 0) ? 0.18033688011112042f : 1.0f;
    const float* src = W + (size_t)h * 65536 + (size_t)d0 * 64;  // [d][hd]
    #pragma unroll
    for (int i = 0; i < 16; ++i) { int r = g * 16 + i; t[r][l] = (bf16_t)(src[(size_t)r * 64 + l] * scl); }
    __syncthreads();
    bf16_t* dst = WT + ((size_t)z * 1024 + h * 64) * 1024 + d0;
    #pragma unroll
    for (int i = 0; i < 16; ++i) { int c = g * 16 + i; dst[(size_t)c * 1024 + l] = t[l][c]; }
  } else {  // Wo [1024][1024] -> WoT
    bx -= 768;
    const int r0 = (bx & 15) * 64, c0 = (bx >> 4) * 64;
    #pragma unroll
    for (int i = 0; i < 16; ++i) { int r = g * 16 + i; t[r][l] = (bf16_t)Wo[(size_t)(r0 + r) * 1024 + c0 + l]; }
    __syncthreads();
    #pragma unroll
    for (int i = 0; i < 16; ++i) { int c = g * 16 + i; WoT[(size_t)(c0 + c) * 1024 + r0 + l] = t[l][c]; }
  }
}

// ---------------------------------------------------------------------------
// GEMM body, BK=64: C[m][n] = sum_k A[m][k]*Bt[n][k] (+f32 bias).
// M-tile 128; N-tile = NT*32. B tile = NT*256 chunks -> NT staging iters.
// NT=4: LDS 32KB (proven). NT=2: LDS 24KB for out_gemm's 2 blocks/CU.
// ---------------------------------------------------------------------------
template <bool BIAS, typename OutT, int NT>
__device__ __forceinline__ void gemm_body(
    const bf16_t* __restrict__ A, const bf16_t* __restrict__ Bt,
    OutT* __restrict__ C, const float* __restrict__ bias,
    int K, int lda, int ldb, int ldc, int m0, int n0,
    bf16_t* As, bf16_t* Bs) {
  const int tid = threadIdx.x;
  const int lane = tid & 63, w = tid >> 6;
  const int qd = lane >> 4, ln = lane & 15;
  const int wm = (w & 1) * 64, wn = (w >> 1) * (NT * 16);

  const floatx4 z4 = {0.f, 0.f, 0.f, 0.f};
  floatx4 acc[4][NT];
  #pragma unroll
  for (int i = 0; i < 4; ++i)
    #pragma unroll
    for (int j = 0; j < NT; ++j) acc[i][j] = z4;

  for (int k0 = 0; k0 < K; k0 += 64) {
    #pragma unroll
    for (int i = 0; i < 4; ++i) {  // A: 128 rows -> 1024 chunks
      const int c = tid + i * 256;
      const int row = c >> 3;
      const int sg = (c & 7) ^ (row & 7);
      GLD16(A + (size_t)(m0 + row) * lda + k0 + sg * 8, As + (size_t)(w * 64 + i * 256) * 8);
    }
    #pragma unroll
    for (int i = 0; i < NT; ++i) {  // B: NT*32 rows -> NT*256 chunks
      const int c = tid + i * 256;
      const int row = c >> 3;
      const int sg = (c & 7) ^ (row & 7);
      GLD16(Bt + (size_t)(n0 + row) * ldb + k0 + sg * 8, Bs + (size_t)(w * 64 + i * 256) * 8);
    }
    __syncthreads();
    #pragma unroll
    for (int h = 0; h < 2; ++h) {
      bf16x8 af[4], bfr[NT];
      #pragma unroll
      for (int t = 0; t < 4; ++t) {
        const int ra = wm + t * 16 + ln;
        af[t]  = *(const bf16x8*)(As + (size_t)ra * 64 + (((h * 4 + qd) ^ (ra & 7)) * 8));
      }
      #pragma unroll
      for (int t = 0; t < NT; ++t) {
        const int rb = wn + t * 16 + ln;
        bfr[t] = *(const bf16x8*)(Bs + (size_t)rb * 64 + (((h * 4 + qd) ^ (rb & 7)) * 8));
      }
      #pragma unroll
      for (int mt = 0; mt < 4; ++mt)
        #pragma unroll
        for (int nt = 0; nt < NT; ++nt)
          acc[mt][nt] = __builtin_amdgcn_mfma_f32_16x16x32_bf16(af[mt], bfr[nt], acc[mt][nt], 0, 0, 0);
    }
    __syncthreads();
  }

  #pragma unroll
  for (int nt = 0; nt < NT; ++nt) {
    const int col = n0 + wn + nt * 16 + ln;
    const float bv = BIAS ? bias[col] : 0.f;
    #pragma unroll
    for (int mt = 0; mt < 4; ++mt) {
      const int row = m0 + wm + mt * 16 + qd * 4;  // C layout: col=lane&15, row=quad*4+reg
      #pragma unroll
      for (int r = 0; r < 4; ++r)
        C[(size_t)(row + r) * ldc + col] = (OutT)(acc[mt][nt][r] + bv);
    }
  }
}

// Fused projections: blocks [0,512) QK gemm (C1[4096][2048]),
// blocks [512,768) V gemm directly transposed (VT[1024][4096]).
__global__ __launch_bounds__(256) void proj_gemm(
    const bf16_t* __restrict__ XB, const bf16_t* __restrict__ WT,
    bf16_t* __restrict__ C1, bf16_t* __restrict__ VT) {
  __shared__ __align__(16) bf16_t As[128 * 64];
  __shared__ __align__(16) bf16_t Bs[128 * 64];
  int bx = blockIdx.x;
  if (bx < 512) {
    gemm_body<false, bf16_t, 4>(XB, WT, C1, nullptr, 1024, 1024, 1024, 2048,
                                (bx & 31) * 128, (bx >> 5) * 128, As, Bs);
  } else {
    bx -= 512;
    gemm_body<false, bf16_t, 4>(WT + (size_t)2048 * 1024, XB, VT, nullptr,
                                1024, 1024, 1024, 4096,
                                (bx & 7) * 128, (bx >> 3) * 128, As, Bs);
  }
}

// Output projection (+bias) -> f32. 128x64 tiles -> 512 blocks = 2/CU.
__global__ __launch_bounds__(256) void out_gemm(
    const bf16_t* __restrict__ AO, const bf16_t* __restrict__ WoT,
    float* __restrict__ C, const float* __restrict__ bias) {
  __shared__ __align__(16) bf16_t As[128 * 64];
  __shared__ __align__(16) bf16_t Bs[64 * 64];
  gemm_body<true, float, 2>(AO, WoT, C, bias, 1024, 1024, 1024, 1024,
                            blockIdx.x * 128, blockIdx.y * 64, As, Bs);
}

// pack two f32 -> one u32 of 2 bf16 (RNE, same as (bf16_t) casts)
__device__ __forceinline__ int pk2(float lo, float hi) {
  bf16x2 t; t[0] = (bf16_t)lo; t[1] = (bf16_t)hi;
  return __builtin_bit_cast(int, t);
}

// ---------------------------------------------------------------------------
// Flash attention v12: 32x32x16 MFMA + in-register softmax (T12 structure).
//  - 2 waves/block (128 thr), wave w owns q-rows [qt*64+w*32, +32). Grid,
//    balance map {j,15-j,16+j,31-j}, XCD-local (b,h), staging layout ALL
//    unchanged from the proven v9.
//  - S^T = mfma_32x32x16(kf, qf): lane holds P[q = lane&31][32 s-slices]
//    in-register -> softmax needs NO LDS Ps (LDS 40960 -> 32768 B) and
//    K/V frag reads cover 2x the q-rows -> LDS frag traffic per q HALVED.
//  - A/B operand layout: lane l: X[row = l&31][k = 8*(l>>5)+j] (same
//    pattern as verified 16x16 usage). C/D: col = l&31,
//    row = (reg&3) + 8*(reg>>2) + 4*(l>>5) (HW-verified m74/m101).
//  - P -> PV A-frags: pack to bf16 pairs + 8 shfl_xor(32) half-exchange
//    (element-verified mapping in MKPA comments).
//  - Row-sums via mfma(pa, ones): osum[reg] = l[q(reg,hh)] lands exactly
//    in O's row layout -> in-lane epilogue divide, no shfl.
//  - 1024 blocks = 4 blocks/CU (LDS 4x32KB=128KB), 8 waves/CU.
// ---------------------------------------------------------------------------
__global__ __launch_bounds__(128, 2) void flash_attn(
    const bf16_t* __restrict__ C1, const bf16_t* __restrict__ VT,
    bf16_t* __restrict__ AO) {
  __shared__ __align__(16) bf16_t Ks[2][64 * 64];  // 16384 B
  __shared__ __align__(16) bf16_t Vs[2][64 * 64];  // 16384 B (total 32768)

  const int bid = blockIdx.x;
  const int g = bid & 31;             // (b,h) group; XCD = g & 7
  const int b = g >> 4, h = g & 15;
  const int v = bid >> 5, j = v & 7, sel = v >> 3;
  const int qt = (sel == 0) ? j : (sel == 1) ? 15 - j : (sel == 2) ? 16 + j : 31 - j;

  const int tid = threadIdx.x, lane = tid & 63, w = tid >> 6;  // w in {0,1}
  const int r32 = lane & 31, hh = lane >> 5;
  const bf16_t* Qb = C1 + (size_t)b * 2048 * 2048;

  // Q B-frags: lane: Q[q = qt*64 + w*32 + r32][d = 16c + 8*hh + j]
  bf16x8 qf[4];
  {
    const bf16_t* qp = Qb + (size_t)(qt * 64 + w * 32 + r32) * 2048 + h * 64 + hh * 8;
    #pragma unroll
    for (int c = 0; c < 4; ++c) qf[c] = *(const bf16x8*)(qp + c * 16);
  }

  floatx16 z16;
  #pragma unroll
  for (int i = 0; i < 16; ++i) z16[i] = 0.f;
  floatx16 oacc0 = z16, oacc1 = z16, osum = z16;
  const bf16_t one = (bf16_t)1.0f;
  const bf16x8 vone = {one, one, one, one, one, one, one, one};

  const bf16_t* Kg = Qb + 1024 + h * 64;                       // + s*2048 + d
  const bf16_t* Vg = VT + (size_t)(h * 64) * 4096 + b * 2048;  // + hd*4096 + t

  // staging (128 thr): thread covers rows r0+16k (k=0..3), slot tid&7;
  // (r0+16k)&7 == r0&7 so one pre-swizzled source col works for all k.
  const int r0 = tid >> 3;
  const int g0 = ((tid & 7) ^ (r0 & 7)) * 8;

  auto STAGE = [&](int BUF, int SOFF) {
    #pragma unroll
    for (int k = 0; k < 4; ++k)
      GLD16(Kg + (size_t)(SOFF + r0 + 16 * k) * 2048 + g0, &Ks[BUF][w * 512 + k * 1024]);
    #pragma unroll
    for (int k = 0; k < 4; ++k)
      GLD16(Vg + (size_t)(r0 + 16 * k) * 4096 + SOFF + g0, &Vs[BUF][w * 512 + k * 1024]);
  };

  STAGE(0, 0);  // prologue: tile 0

  const int fk = r32 & 7;  // frag-read swizzle key (row&7, same for row+32)

  for (int st = 0; st <= qt; ++st) {
    const int bi = st & 1;
    __syncthreads();  // drains vmcnt: tile st staged; WAR-safe for buf bi^1
    if (st < qt) STAGE(bi ^ 1, (st + 1) * 64);

    // QK^T: p0 = S^T[s=0..31][q], p1 = S^T[s=32..63][q]; q = r32 lane-local
    floatx16 p0 = z16, p1 = z16;
    __builtin_amdgcn_s_setprio(1);
    #pragma unroll
    for (int c = 0; c < 4; ++c) {
      const int sl = ((2 * c + hh) ^ fk) * 8;
      bf16x8 kf0 = *(const bf16x8*)(&Ks[bi][r32 * 64 + sl]);
      bf16x8 kf1 = *(const bf16x8*)(&Ks[bi][(32 + r32) * 64 + sl]);
      p0 = __builtin_amdgcn_mfma_f32_32x32x16_bf16(kf0, qf[c], p0, 0, 0, 0);
      p1 = __builtin_amdgcn_mfma_f32_32x32x16_bf16(kf1, qf[c], p1, 0, 0, 0);
    }
    __builtin_amdgcn_s_setprio(0);

    // softmax (no max-subtract; Q pre-scaled): mask only at st==qt.
    // lane's P rows: s = (reg&3) + 8*(reg>>2) + 4*hh (+32 for p1).
    const int qloc = w * 32 + r32;
    #pragma unroll
    for (int reg = 0; reg < 16; ++reg) {
      const int srow = (reg & 3) + 8 * (reg >> 2) + 4 * hh;
      float a = p0[reg], c2 = p1[reg];
      if (st == qt) {
        if (srow > qloc) a = -1e30f;
        if (32 + srow > qloc) c2 = -1e30f;
      }
      p0[reg] = __builtin_amdgcn_exp2f(a);
      p1[reg] = __builtin_amdgcn_exp2f(c2);
    }

    // P -> bf16 A-frags, in-register (verified element map):
    // own u32s (lane hh): u0=(4hh,4hh+1) u1=(4hh+2,4hh+3) u2=(4hh+8,4hh+9)
    // u3=(4hh+10,11) u4=(4hh+16,17) u5=(4hh+18,19) u6=(4hh+24,25) u7=(4hh+26,27).
    // chunk A (s 0..15) lane hh needs s 8hh..8hh+7; chunk B s 16..31 ditto.
    bf16x8 pa[4];
    {
      auto MKPA = [&](const floatx16& e, bf16x8& A8, bf16x8& B8) {
        int u0 = pk2(e[0], e[1]),  u1 = pk2(e[2], e[3]);
        int u2 = pk2(e[4], e[5]),  u3 = pk2(e[6], e[7]);
        int u4 = pk2(e[8], e[9]),  u5 = pk2(e[10], e[11]);
        int u6 = pk2(e[12], e[13]), u7 = pk2(e[14], e[15]);
        // hh=0 sends u2,u3,u6,u7 (s 8..11,24..27); hh=1 sends u0,u1,u4,u5 (s 4..7,20..23)
        int s0 = __shfl_xor(hh ? u0 : u2, 32);  // hh=0 rx (4,5);  hh=1 rx (8,9)
        int s1 = __shfl_xor(hh ? u1 : u3, 32);  // hh=0 rx (6,7);  hh=1 rx (10,11)
        int s2 = __shfl_xor(hh ? u4 : u6, 32);  // hh=0 rx (20,21); hh=1 rx (24,25)
        int s3 = __shfl_xor(hh ? u5 : u7, 32);  // hh=0 rx (22,23); hh=1 rx (26,27)
        intx4 A, B;
        A[0] = hh ? s0 : u0;  A[1] = hh ? s1 : u1;   // hh=0:(0,1)(2,3)  hh=1:(8,9)(10,11)
        A[2] = hh ? u2 : s0;  A[3] = hh ? u3 : s1;   // hh=0:(4,5)(6,7)  hh=1:(12,13)(14,15)
        B[0] = hh ? s2 : u4;  B[1] = hh ? s3 : u5;   // hh=0:(16,17)(18,19) hh=1:(24,25)(26,27)
        B[2] = hh ? u6 : s2;  B[3] = hh ? u7 : s3;   // hh=0:(20,21)(22,23) hh=1:(28,29)(30,31)
        A8 = __builtin_bit_cast(bf16x8, A);
        B8 = __builtin_bit_cast(bf16x8, B);
      };
      MKPA(p0, pa[0], pa[1]);  // s 0..15, 16..31
      MKPA(p1, pa[2], pa[3]);  // s 32..47, 48..63
    }

    // PV: O[q][hd] += P*V; osum += P*1 (row sums on the MFMA pipe)
    __builtin_amdgcn_s_setprio(1);
    #pragma unroll
    for (int c = 0; c < 4; ++c) {
      const int sl = ((2 * c + hh) ^ fk) * 8;
      bf16x8 vf0 = *(const bf16x8*)(&Vs[bi][r32 * 64 + sl]);         // hd 0..31
      bf16x8 vf1 = *(const bf16x8*)(&Vs[bi][(32 + r32) * 64 + sl]);  // hd 32..63
      oacc0 = __builtin_amdgcn_mfma_f32_32x32x16_bf16(pa[c], vf0, oacc0, 0, 0, 0);
      oacc1 = __builtin_amdgcn_mfma_f32_32x32x16_bf16(pa[c], vf1, oacc1, 0, 0, 0);
      osum  = __builtin_amdgcn_mfma_f32_32x32x16_bf16(pa[c], vone, osum, 0, 0, 0);
    }
    __builtin_amdgcn_s_setprio(0);
  }

  // epilogue: O[q][hd] /= l[q]; osum[reg] = l[q(reg,hh)] in-lane.
  #pragma unroll
  for (int reg = 0; reg < 16; ++reg) {
    const float lr = 1.0f / osum[reg];
    const int qrow = (reg & 3) + 8 * (reg >> 2) + 4 * hh;
    const size_t row = (size_t)(b * 2048 + qt * 64 + w * 32 + qrow);
    AO[row * 1024 + h * 64 + r32]      = (bf16_t)(oacc0[reg] * lr);
    AO[row * 1024 + h * 64 + 32 + r32] = (bf16_t)(oacc1[reg] * lr);
  }
}

// ---------------------------------------------------------------------------
extern "C" void kernel_launch(void* const* d_in, const int* in_sizes, int n_in,
                              void* d_out, int out_size, void* d_ws, size_t ws_size,
                              hipStream_t stream) {
  const float* x  = (const float*)d_in[0];
  const float* Wq = (const float*)d_in[1];
  const float* Wk = (const float*)d_in[2];
  const float* Wv = (const float*)d_in[3];
  const float* Wo = (const float*)d_in[4];
  const float* bo = (const float*)d_in[5];
  float* out = (float*)d_out;

  // Workspace (33.56 MB, proven safe):
  bf16_t* WT  = (bf16_t*)d_ws;               // [3072][1024] 6.29 MB (Q|K|V weight rows)
  bf16_t* WoT = WT + (size_t)3072 * 1024;    // [1024][1024] 2.10 MB
  bf16_t* C1  = WoT + (size_t)1024 * 1024;   // [4096][2048] 16.78 MB (Q|K cols)
  bf16_t* AO  = C1 + (size_t)4096 * 2048;    // [4096][1024] 8.39 MB
  // d_out doubles as scratch (16.78 MB; fully overwritten by final gemm):
  bf16_t* XB  = (bf16_t*)d_out;              // [4096][1024] bf16, lower half
  bf16_t* VT  = XB + (size_t)4096 * 1024;    // [1024][4096] bf16, upper half

  prep<<<dim3(3072), 256, 0, stream>>>(x, Wq, Wk, Wv, Wo, XB, WT, WoT);
  proj_gemm<<<dim3(768), 256, 0, stream>>>(XB, WT, C1, VT);
  flash_attn<<<dim3(1024), 128, 0, stream>>>(C1, VT, AO);
  out_gemm<<<dim3(32, 16), 256, 0, stream>>>(AO, WoT, out, bo);
}

// Round 14
// 164.722 us; speedup vs baseline: 1.0684x; 1.0684x over previous
//
#include <hip/hip_runtime.h>
#include <hip/hip_bf16.h>
#include <stdint.h>
#include <stddef.h>

typedef __bf16 bf16_t;
typedef __attribute__((ext_vector_type(4))) __bf16 bf16x4;
typedef __attribute__((ext_vector_type(8))) __bf16 bf16x8;
typedef __attribute__((ext_vector_type(4))) float floatx4;

#define GLD16(gp, lp) __builtin_amdgcn_global_load_lds(                      \
    (__attribute__((address_space(1))) void*)(gp),                           \
    (__attribute__((address_space(3))) void*)(lp), 16, 0, 0)

// ---------------------------------------------------------------------------
// Fused prep: [0,2048) x f32->bf16 | [2048,2816) transpose_w | [2816,3072) transpose_wo
// Q weights (z==0) pre-scaled by (1/sqrt(64))*log2(e).
// ---------------------------------------------------------------------------
__global__ __launch_bounds__(256) void prep(
    const float* __restrict__ x, const float* __restrict__ Wq,
    const float* __restrict__ Wk, const float* __restrict__ Wv,
    const float* __restrict__ Wo, bf16_t* __restrict__ XB,
    bf16_t* __restrict__ WT, bf16_t* __restrict__ WoT) {
  __shared__ bf16_t t[64][65];
  int bx = blockIdx.x;
  const int tid = threadIdx.x;
  if (bx < 2048) {  // convert x
    const int i = (bx * 256 + tid) * 8;
    const float4 v0 = *(const float4*)(x + i);
    const float4 v1 = *(const float4*)(x + i + 4);
    bf16x8 o = {(bf16_t)v0.x, (bf16_t)v0.y, (bf16_t)v0.z, (bf16_t)v0.w,
                (bf16_t)v1.x, (bf16_t)v1.y, (bf16_t)v1.z, (bf16_t)v1.w};
    *(bf16x8*)(XB + i) = o;
    return;
  }
  bx -= 2048;
  const int g = tid >> 6, l = tid & 63;
  if (bx < 768) {  // Wq/Wk/Wv [16][1024][64] -> WT [3072][1024]
    const int d0 = (bx & 15) * 64, h = (bx >> 4) & 15, z = bx >> 8;
    const float* W = (z == 0) ? Wq : (z == 1) ? Wk : Wv;
    const float scl = (z == 0) ? 0.18033688011112042f : 1.0f;
    const float* src = W + (size_t)h * 65536 + (size_t)d0 * 64;  // [d][hd]
    #pragma unroll
    for (int i = 0; i < 16; ++i) { int r = g * 16 + i; t[r][l] = (bf16_t)(src[(size_t)r * 64 + l] * scl); }
    __syncthreads();
    bf16_t* dst = WT + ((size_t)z * 1024 + h * 64) * 1024 + d0;
    #pragma unroll
    for (int i = 0; i < 16; ++i) { int c = g * 16 + i; dst[(size_t)c * 1024 + l] = t[l][c]; }
  } else {  // Wo [1024][1024] -> WoT
    bx -= 768;
    const int r0 = (bx & 15) * 64, c0 = (bx >> 4) * 64;
    #pragma unroll
    for (int i = 0; i < 16; ++i) { int r = g * 16 + i; t[r][l] = (bf16_t)Wo[(size_t)(r0 + r) * 1024 + c0 + l]; }
    __syncthreads();
    #pragma unroll
    for (int i = 0; i < 16; ++i) { int c = g * 16 + i; WoT[(size_t)(c0 + c) * 1024 + r0 + l] = t[l][c]; }
  }
}

// ---------------------------------------------------------------------------
// GEMM body, BK=64: C[m][n] = sum_k A[m][k]*Bt[n][k] (+f32 bias).
// M-tile 128; N-tile = NT*32. B tile = NT*256 chunks -> NT staging iters.
// NT=4: LDS 32KB (proven). NT=2: LDS 24KB for out_gemm's 2 blocks/CU.
// ---------------------------------------------------------------------------
template <bool BIAS, typename OutT, int NT>
__device__ __forceinline__ void gemm_body(
    const bf16_t* __restrict__ A, const bf16_t* __restrict__ Bt,
    OutT* __restrict__ C, const float* __restrict__ bias,
    int K, int lda, int ldb, int ldc, int m0, int n0,
    bf16_t* As, bf16_t* Bs) {
  const int tid = threadIdx.x;
  const int lane = tid & 63, w = tid >> 6;
  const int qd = lane >> 4, ln = lane & 15;
  const int wm = (w & 1) * 64, wn = (w >> 1) * (NT * 16);

  const floatx4 z4 = {0.f, 0.f, 0.f, 0.f};
  floatx4 acc[4][NT];
  #pragma unroll
  for (int i = 0; i < 4; ++i)
    #pragma unroll
    for (int j = 0; j < NT; ++j) acc[i][j] = z4;

  for (int k0 = 0; k0 < K; k0 += 64) {
    #pragma unroll
    for (int i = 0; i < 4; ++i) {  // A: 128 rows -> 1024 chunks
      const int c = tid + i * 256;
      const int row = c >> 3;
      const int sg = (c & 7) ^ (row & 7);
      GLD16(A + (size_t)(m0 + row) * lda + k0 + sg * 8, As + (size_t)(w * 64 + i * 256) * 8);
    }
    #pragma unroll
    for (int i = 0; i < NT; ++i) {  // B: NT*32 rows -> NT*256 chunks
      const int c = tid + i * 256;
      const int row = c >> 3;
      const int sg = (c & 7) ^ (row & 7);
      GLD16(Bt + (size_t)(n0 + row) * ldb + k0 + sg * 8, Bs + (size_t)(w * 64 + i * 256) * 8);
    }
    __syncthreads();
    #pragma unroll
    for (int h = 0; h < 2; ++h) {
      bf16x8 af[4], bfr[NT];
      #pragma unroll
      for (int t = 0; t < 4; ++t) {
        const int ra = wm + t * 16 + ln;
        af[t]  = *(const bf16x8*)(As + (size_t)ra * 64 + (((h * 4 + qd) ^ (ra & 7)) * 8));
      }
      #pragma unroll
      for (int t = 0; t < NT; ++t) {
        const int rb = wn + t * 16 + ln;
        bfr[t] = *(const bf16x8*)(Bs + (size_t)rb * 64 + (((h * 4 + qd) ^ (rb & 7)) * 8));
      }
      #pragma unroll
      for (int mt = 0; mt < 4; ++mt)
        #pragma unroll
        for (int nt = 0; nt < NT; ++nt)
          acc[mt][nt] = __builtin_amdgcn_mfma_f32_16x16x32_bf16(af[mt], bfr[nt], acc[mt][nt], 0, 0, 0);
    }
    __syncthreads();
  }

  #pragma unroll
  for (int nt = 0; nt < NT; ++nt) {
    const int col = n0 + wn + nt * 16 + ln;
    const float bv = BIAS ? bias[col] : 0.f;
    #pragma unroll
    for (int mt = 0; mt < 4; ++mt) {
      const int row = m0 + wm + mt * 16 + qd * 4;  // C layout: col=lane&15, row=quad*4+reg
      #pragma unroll
      for (int r = 0; r < 4; ++r)
        C[(size_t)(row + r) * ldc + col] = (OutT)(acc[mt][nt][r] + bv);
    }
  }
}

// Fused projections: blocks [0,512) QK gemm (C1[4096][2048]),
// blocks [512,768) V gemm directly transposed (VT[1024][4096]).
__global__ __launch_bounds__(256) void proj_gemm(
    const bf16_t* __restrict__ XB, const bf16_t* __restrict__ WT,
    bf16_t* __restrict__ C1, bf16_t* __restrict__ VT) {
  __shared__ __align__(16) bf16_t As[128 * 64];
  __shared__ __align__(16) bf16_t Bs[128 * 64];
  int bx = blockIdx.x;
  if (bx < 512) {
    gemm_body<false, bf16_t, 4>(XB, WT, C1, nullptr, 1024, 1024, 1024, 2048,
                                (bx & 31) * 128, (bx >> 5) * 128, As, Bs);
  } else {
    bx -= 512;
    gemm_body<false, bf16_t, 4>(WT + (size_t)2048 * 1024, XB, VT, nullptr,
                                1024, 1024, 1024, 4096,
                                (bx & 7) * 128, (bx >> 3) * 128, As, Bs);
  }
}

// Output projection (+bias) -> f32. 128x64 tiles -> 512 blocks = 2/CU
// (256 = 1/CU was latency-bound: 1 wave/SIMD, nothing to hide GLD16 under).
__global__ __launch_bounds__(256) void out_gemm(
    const bf16_t* __restrict__ AO, const bf16_t* __restrict__ WoT,
    float* __restrict__ C, const float* __restrict__ bias) {
  __shared__ __align__(16) bf16_t As[128 * 64];
  __shared__ __align__(16) bf16_t Bs[64 * 64];
  gemm_body<true, float, 2>(AO, WoT, C, bias, 1024, 1024, 1024, 1024,
                            blockIdx.x * 128, blockIdx.y * 64, As, Bs);
}

// ---------------------------------------------------------------------------
// Flash attention v9 (measured best, verbatim):
//  - XCD-local (b,h) mapping (g = bid&31 -> (b,h); XCD = g&7 constant per
//    (b,h); co-CU blocks share the SAME (b,h) -> K/V L2/L1-local).
//  - Balance map {j, 15-j, 16+j, 31-j}: per-CU qt-set degrades 4->3->2->1
//    blocks gradually. (Split-K, tile-peel, and 32x32 restructures all
//    measured worse or failed: flash is LDS-throughput-bound at this
//    structure's local optimum.)
//  - Ones-MFMA row-sum on the MFMA pipe; V-frag preload before softmax;
//    s_setprio(1) around MFMA clusters.
//  - LDS 40960 B -> 4 blocks/CU; K/V XOR-slot-swizzled via pre-swizzled
//    global source + linear GLD16 dest; Ps 8B-slot swizzle; Q pre-scaled.
// ---------------------------------------------------------------------------
__global__ __launch_bounds__(256, 4) void flash_attn(
    const bf16_t* __restrict__ C1, const bf16_t* __restrict__ VT,
    bf16_t* __restrict__ AO) {
  __shared__ __align__(16) bf16_t Ks[2][64 * 64];  // 16384 B
  __shared__ __align__(16) bf16_t Vs[2][64 * 64];  // 16384 B
  __shared__ __align__(16) bf16_t Ps[4][16 * 64];  //  8192 B  (total 40960)

  const int bid = blockIdx.x;
  const int g = bid & 31;             // (b,h) group; XCD = g & 7
  const int b = g >> 4, h = g & 15;
  const int v = bid >> 5, j = v & 7, sel = v >> 3;
  const int qt = (sel == 0) ? j : (sel == 1) ? 15 - j : (sel == 2) ? 16 + j : 31 - j;

  const int tid = threadIdx.x, lane = tid & 63, w = tid >> 6;
  const int qd = lane >> 4, ln = lane & 15;
  const bf16_t* Qb = C1 + (size_t)b * 2048 * 2048;

  // Q B-frags: lane (qd,ln): col=ln -> q, k=qd*8+j -> d (pre-scaled by SCL)
  bf16x8 qf0, qf1;
  {
    const bf16_t* qp = Qb + (size_t)(qt * 64 + w * 16 + ln) * 2048 + h * 64 + qd * 8;
    qf0 = *(const bf16x8*)qp;
    qf1 = *(const bf16x8*)(qp + 32);
  }
  const floatx4 z4 = {0.f, 0.f, 0.f, 0.f};
  floatx4 oacc[4];  // [t][r]: O[q_local=qd*4+r][hd=t*16+ln]
  #pragma unroll
  for (int t = 0; t < 4; ++t) oacc[t] = z4;
  floatx4 osum = z4;  // osum[r] = sum_s P[q=4qd+r][s], replicated over ln
  const bf16_t one = (bf16_t)1.0f;
  const bf16x8 vone = {one, one, one, one, one, one, one, one};

  const bf16_t* Kg = Qb + 1024 + h * 64;                       // + s*2048 + d
  const bf16_t* Vg = VT + (size_t)(h * 64) * 4096 + b * 2048;  // + hd*4096 + t

  const int r0 = tid >> 3;
  const int g0 = ((tid & 7) ^ (r0 & 7)) * 8;

  auto STAGE = [&](int BUF, int SOFF) {
    GLD16(Kg + (size_t)(SOFF + r0) * 2048 + g0,      &Ks[BUF][w * 512]);
    GLD16(Kg + (size_t)(SOFF + r0 + 32) * 2048 + g0, &Ks[BUF][w * 512 + 2048]);
    GLD16(Vg + (size_t)r0 * 4096 + SOFF + g0,        &Vs[BUF][w * 512]);
    GLD16(Vg + (size_t)(r0 + 32) * 4096 + SOFF + g0, &Vs[BUF][w * 512 + 2048]);
  };

  STAGE(0, 0);  // prologue: tile 0

  const int e2 = (ln & 7) << 1;       // Ps 8B-slot swizzle key
  const int swf = qd ^ (ln & 7);      // K/V frag slot swizzle (row&7 == ln&7)

  for (int st = 0; st <= qt; ++st) {
    const int bi = st & 1;
    __syncthreads();  // drains vmcnt: tile st staged; WAR-safe for buf bi^1
    if (st < qt) STAGE(bi ^ 1, (st + 1) * 64);

    // S^T = K Q^T : lane (qd,ln) gets P[q=ln][s=nt*16+qd*4+r]
    floatx4 sa[4];
    __builtin_amdgcn_s_setprio(1);
    #pragma unroll
    for (int nt = 0; nt < 4; ++nt) {
      const bf16_t* kp = &Ks[bi][(nt * 16 + ln) * 64];
      bf16x8 kf0 = *(const bf16x8*)(kp + swf * 8);
      bf16x8 kf1 = *(const bf16x8*)(kp + (swf ^ 4) * 8);
      floatx4 t0 = z4;
      t0 = __builtin_amdgcn_mfma_f32_16x16x32_bf16(kf0, qf0, t0, 0, 0, 0);
      t0 = __builtin_amdgcn_mfma_f32_16x16x32_bf16(kf1, qf1, t0, 0, 0, 0);
      sa[nt] = t0;
    }
    __builtin_amdgcn_s_setprio(0);

    // V-frag preload (independent of Ps round-trip): PV can start the
    // moment pa0/pa1 land.
    bf16x8 vf0[4], vf1[4];
    #pragma unroll
    for (int t = 0; t < 4; ++t) {
      const bf16_t* vp = &Vs[bi][(t * 16 + ln) * 64];
      vf0[t] = *(const bf16x8*)(vp + swf * 8);
      vf1[t] = *(const bf16x8*)(vp + (swf ^ 4) * 8);
    }

    // softmax -> Ps (swizzled, wave-private; in-wave DS order)
    #pragma unroll
    for (int nt = 0; nt < 4; ++nt) {
      float p[4];
      #pragma unroll
      for (int r = 0; r < 4; ++r) {
        float v2 = sa[nt][r];
        if (st == qt && (nt * 16 + qd * 4 + r) > (w * 16 + ln)) v2 = -1e30f;
        p[r] = __builtin_amdgcn_exp2f(v2);
      }
      bf16x4 pk = {(bf16_t)p[0], (bf16_t)p[1], (bf16_t)p[2], (bf16_t)p[3]};
      *(bf16x4*)(&Ps[w][ln * 64 + (((nt * 4 + qd) ^ e2) << 2)]) = pk;
    }
    bf16x8 pa0 = *(const bf16x8*)(&Ps[w][ln * 64 + ((((qd << 1)    ) ^ e2) << 2)]);
    bf16x8 pa1 = *(const bf16x8*)(&Ps[w][ln * 64 + ((((qd << 1) + 8) ^ e2) << 2)]);

    // PV: oacc += P * V;  osum += P * 1 (row sums on the MFMA pipe)
    __builtin_amdgcn_s_setprio(1);
    #pragma unroll
    for (int t = 0; t < 4; ++t) {
      oacc[t] = __builtin_amdgcn_mfma_f32_16x16x32_bf16(pa0, vf0[t], oacc[t], 0, 0, 0);
      oacc[t] = __builtin_amdgcn_mfma_f32_16x16x32_bf16(pa1, vf1[t], oacc[t], 0, 0, 0);
    }
    osum = __builtin_amdgcn_mfma_f32_16x16x32_bf16(pa0, vone, osum, 0, 0, 0);
    osum = __builtin_amdgcn_mfma_f32_16x16x32_bf16(pa1, vone, osum, 0, 0, 0);
    __builtin_amdgcn_s_setprio(0);
  }

  // epilogue: O[q][hd] /= l[q]; osum[r] already holds l(q=4qd+r) in-lane
  #pragma unroll
  for (int r = 0; r < 4; ++r) {
    const float lr = 1.0f / osum[r];
    #pragma unroll
    for (int t = 0; t < 4; ++t) {
      const int col = h * 64 + t * 16 + ln;
      const int row = b * 2048 + qt * 64 + w * 16 + qd * 4 + r;
      AO[(size_t)row * 1024 + col] = (bf16_t)(oacc[t][r] * lr);
    }
  }
}

// ---------------------------------------------------------------------------
extern "C" void kernel_launch(void* const* d_in, const int* in_sizes, int n_in,
                              void* d_out, int out_size, void* d_ws, size_t ws_size,
                              hipStream_t stream) {
  const float* x  = (const float*)d_in[0];
  const float* Wq = (const float*)d_in[1];
  const float* Wk = (const float*)d_in[2];
  const float* Wv = (const float*)d_in[3];
  const float* Wo = (const float*)d_in[4];
  const float* bo = (const float*)d_in[5];
  float* out = (float*)d_out;

  // Workspace (33.56 MB, proven safe):
  bf16_t* WT  = (bf16_t*)d_ws;               // [3072][1024] 6.29 MB (Q|K|V weight rows)
  bf16_t* WoT = WT + (size_t)3072 * 1024;    // [1024][1024] 2.10 MB
  bf16_t* C1  = WoT + (size_t)1024 * 1024;   // [4096][2048] 16.78 MB (Q|K cols)
  bf16_t* AO  = C1 + (size_t)4096 * 2048;    // [4096][1024] 8.39 MB
  // d_out doubles as scratch (16.78 MB; fully overwritten by final gemm):
  bf16_t* XB  = (bf16_t*)d_out;              // [4096][1024] bf16, lower half
  bf16_t* VT  = XB + (size_t)4096 * 1024;    // [1024][4096] bf16, upper half

  prep<<<dim3(3072), 256, 0, stream>>>(x, Wq, Wk, Wv, Wo, XB, WT, WoT);
  proj_gemm<<<dim3(768), 256, 0, stream>>>(XB, WT, C1, VT);
  flash_attn<<<dim3(1024), 256, 0, stream>>>(C1, VT, AO);
  out_gemm<<<dim3(32, 16), 256, 0, stream>>>(AO, WoT, out, bo);
}